// Round 3
// baseline (243.911 us; speedup 1.0000x reference)
//
#include <hip/hip_runtime.h>
#include <math.h>

// Problem constants (fixed by the reference): ip (8, 256, 128, 128) fp32.
#define NB   8
#define NC   256
#define NHW  (128 * 128)

// Structure: Out[c,p] = sum_k M[c,k] X[k,p], M = 256x256 DCT-III matrix.
// Symmetry: M[255-c][k] = (-1)^k M[c][k]  -> store only c=0..127 (64 KB bf16),
// compute the mirror half with sign-flipped X fragments (XOR 0x80000000/dword).
//
// Block: 512 threads = 8 waves (4 c-strips x 2 p-halves), persistent over
// TILES=4 p-tiles of 64 columns. LDS = A 64 KB (resident, loaded once) +
// X double-buffer 2x32 KB = 128 KiB. ONE barrier per tile (K fully resident).
#define TILES 4
#define XB 65536          // X buffers at [65536,98304) and [98304,131072)

typedef __attribute__((ext_vector_type(4))) float f32x4;
typedef __attribute__((ext_vector_type(8))) short bf16x8;
typedef __attribute__((ext_vector_type(4))) unsigned int u32x4;

__device__ __forceinline__ unsigned short f2bf(float f) {
    unsigned u = __builtin_bit_cast(unsigned, f);
    u += 0x7fffu + ((u >> 16) & 1u);
    return (unsigned short)(u >> 16);
}

__device__ __forceinline__ unsigned pack2bf(float a, float b) {
    unsigned lo = __builtin_bit_cast(unsigned, a);
    lo += 0x7fffu + ((lo >> 16) & 1u);
    unsigned hi = __builtin_bit_cast(unsigned, b);
    hi += 0x7fffu + ((hi >> 16) & 1u);
    return (lo >> 16) | (hi & 0xffff0000u);
}

// Flip sign of odd-k bf16 elements: dword = (even k | odd k<<16) -> XOR bit 31.
__device__ __forceinline__ bf16x8 flip_odd(bf16x8 b) {
    u32x4 u = __builtin_bit_cast(u32x4, b);
    u ^= (u32x4){0x80000000u, 0x80000000u, 0x80000000u, 0x80000000u};
    return __builtin_bit_cast(bf16x8, u);
}

// DCT-III coefficients, rows c = 0..127 only. M[c][k] = (k==0)?1:2cos(pi*k*(2c+1)/512).
__global__ void coef_kernel(unsigned short* __restrict__ coef) {
    int idx = blockIdx.x * 256 + threadIdx.x;     // 0..32767
    int c = idx >> 8;
    int k = idx & 255;
    int t = (k * (2 * c + 1)) & 1023;
    float v = (k == 0) ? 1.0f : 2.0f * cosf((float)t * (float)(M_PI / 512.0));
    coef[idx] = f2bf(v);
}

__device__ __forceinline__ void gload_lds16(const void* g, void* l) {
    __builtin_amdgcn_global_load_lds(
        (const __attribute__((address_space(1))) unsigned int*)g,
        (__attribute__((address_space(3))) unsigned int*)l,
        16, 0, 0);
}

// LDS rows are 512 B (256 bf16 = full K). 32 16-B slots/row; logical slot s of
// row r stored at s ^ (r & 15)  -> all b128 reads/writes hit every bank <=2x (free).

__global__ __launch_bounds__(512, 2)
void dct_gemm(const float* __restrict__ X, const unsigned short* __restrict__ Mcoef,
              float* __restrict__ Out) {
    __shared__ __align__(16) unsigned char lds[131072];

    const int tid  = threadIdx.x;
    const int lane = tid & 63;
    const int wave = tid >> 6;
    const int m16  = lane & 15;
    const int quad = lane >> 4;
    const int wm   = wave >> 1;       // 0..3: 32-row strip of stored A
    const int wn   = wave & 1;        // 0..1: 32-col p-half

    // ---- A load, ONCE per block: linear LDS dest, pre-swizzled global source ----
#pragma unroll
    for (int i = 0; i < 8; i++) {
        const int L = i * 8192 + tid * 16;            // linear dest byte
        const int row = L >> 9;
        const int sl = ((L >> 4) & 31) ^ (row & 15);  // logical slot at this dest
        gload_lds16(Mcoef + row * 256 + sl * 8, lds + L);
    }

    // ---- X staging role: p = tid&63, k = wave*32 + j (j=0..31) ----
    const int sp  = tid & 63;
    const int skb = wave * 32;

    const int g0 = blockIdx.x * TILES;   // global tile ids g0..g0+3; tile: batch=g>>8, ptile=g&255

    // ---- prologue: stage tile g0 into buf 0 ----
    {
        const float* s = X + (size_t)(g0 >> 8) * (NC * NHW) + (size_t)skb * NHW + (g0 & 255) * 64 + sp;
        float v[32];
#pragma unroll
        for (int j = 0; j < 32; j++) v[j] = s[(size_t)j * NHW];   // 256 B/wave coalesced
#pragma unroll
        for (int w = 0; w < 4; w++) {
            int4 q = { (int)pack2bf(v[8*w+0], v[8*w+1]), (int)pack2bf(v[8*w+2], v[8*w+3]),
                       (int)pack2bf(v[8*w+4], v[8*w+5]), (int)pack2bf(v[8*w+6], v[8*w+7]) };
            *(int4*)(lds + XB + sp * 512 + (((wave * 4 + w) ^ (sp & 15)) << 4)) = q;
        }
    }
    __syncthreads();   // drains A gloads + makes X tile 0 visible

    const int aB0 = (wm * 32 + m16) * 512;   // A frag row base (mt adds 16*512)
    const int xB0 = (wn * 32 + m16) * 512;   // X frag row base within buffer

    for (int t = 0; t < TILES; t++) {
        const int g = g0 + t;
        const unsigned char* Xc = lds + XB + (t & 1) * 32768;
        unsigned char* Xs = lds + XB + ((t + 1) & 1) * 32768;

        // prefetch next tile's X into registers (consumed after compute)
        float v[32];
        if (t + 1 < TILES) {
            const int g1 = g + 1;
            const float* s = X + (size_t)(g1 >> 8) * (NC * NHW) + (size_t)skb * NHW + (g1 & 255) * 64 + sp;
#pragma unroll
            for (int j = 0; j < 32; j++) v[j] = s[(size_t)j * NHW];
        }

        f32x4 acc[2][2][2];
#pragma unroll
        for (int a = 0; a < 2; a++)
#pragma unroll
            for (int b = 0; b < 2; b++)
#pragma unroll
                for (int h = 0; h < 2; h++) acc[a][b][h] = (f32x4){0.f, 0.f, 0.f, 0.f};

        // ---- full K = 256 in one phase: 8 chunks x 8 MFMA ----
#pragma unroll
        for (int kk = 0; kk < 8; kk++) {
            const int so = (((kk * 4 + quad) ^ m16) << 4);
            bf16x8 af0 = *(const bf16x8*)(lds + aB0 + so);
            bf16x8 af1 = *(const bf16x8*)(lds + aB0 + 16 * 512 + so);
            bf16x8 bf0 = *(const bf16x8*)(Xc + xB0 + so);
            bf16x8 bf1 = *(const bf16x8*)(Xc + xB0 + 16 * 512 + so);
            bf16x8 bn0 = flip_odd(bf0);
            bf16x8 bn1 = flip_odd(bf1);
            acc[0][0][0] = __builtin_amdgcn_mfma_f32_16x16x32_bf16(af0, bf0, acc[0][0][0], 0, 0, 0);
            acc[0][1][0] = __builtin_amdgcn_mfma_f32_16x16x32_bf16(af0, bf1, acc[0][1][0], 0, 0, 0);
            acc[1][0][0] = __builtin_amdgcn_mfma_f32_16x16x32_bf16(af1, bf0, acc[1][0][0], 0, 0, 0);
            acc[1][1][0] = __builtin_amdgcn_mfma_f32_16x16x32_bf16(af1, bf1, acc[1][1][0], 0, 0, 0);
            acc[0][0][1] = __builtin_amdgcn_mfma_f32_16x16x32_bf16(af0, bn0, acc[0][0][1], 0, 0, 0);
            acc[0][1][1] = __builtin_amdgcn_mfma_f32_16x16x32_bf16(af0, bn1, acc[0][1][1], 0, 0, 0);
            acc[1][0][1] = __builtin_amdgcn_mfma_f32_16x16x32_bf16(af1, bn0, acc[1][0][1], 0, 0, 0);
            acc[1][1][1] = __builtin_amdgcn_mfma_f32_16x16x32_bf16(af1, bn1, acc[1][1][1], 0, 0, 0);
        }

        // ---- write staged X for t+1 (other buffer; its last readers finished
        //      before the PREVIOUS barrier, so this is race-free) ----
        if (t + 1 < TILES) {
#pragma unroll
            for (int w = 0; w < 4; w++) {
                int4 q = { (int)pack2bf(v[8*w+0], v[8*w+1]), (int)pack2bf(v[8*w+2], v[8*w+3]),
                           (int)pack2bf(v[8*w+4], v[8*w+5]), (int)pack2bf(v[8*w+6], v[8*w+7]) };
                *(int4*)(Xs + sp * 512 + (((wave * 4 + w) ^ (sp & 15)) << 4)) = q;
            }
        }

        // ---- store: lo half rows cL..cL+3, mirror half rows 255-cL-3..255-cL ----
        float* Ob = Out + (size_t)(g >> 8) * (NC * NHW) + (g & 255) * 64;
#pragma unroll
        for (int mt = 0; mt < 2; mt++) {
            const int cL = wm * 32 + mt * 16 + quad * 4;
#pragma unroll
            for (int nt = 0; nt < 2; nt++) {
                const int pp = wn * 32 + nt * 16 + m16;
#pragma unroll
                for (int r = 0; r < 4; r++) {
                    Ob[(size_t)(cL + r) * NHW + pp]       = acc[mt][nt][0][r];
                    Ob[(size_t)(255 - cL - r) * NHW + pp] = acc[mt][nt][1][r];
                }
            }
        }

        if (t + 1 < TILES) __syncthreads();   // ONE barrier per tile
    }
}

extern "C" void kernel_launch(void* const* d_in, const int* in_sizes, int n_in,
                              void* d_out, int out_size, void* d_ws, size_t ws_size,
                              hipStream_t stream) {
    const float* ip = (const float*)d_in[0];
    float* out = (float*)d_out;
    unsigned short* coef = (unsigned short*)d_ws;   // 128*256*2 = 64 KB of scratch

    // must redo every launch: d_ws is re-poisoned before each timed call
    coef_kernel<<<dim3(128), dim3(256), 0, stream>>>(coef);

    // 512 persistent blocks x 4 tiles = 2048 tiles = (NHW/64) * NB
    dct_gemm<<<dim3(512), dim3(512), 0, stream>>>(ip, coef, out);
}